// Round 4
// baseline (477.191 us; speedup 1.0000x reference)
//
#include <hip/hip_runtime.h>
#include <hip/hip_bf16.h>

#define IN_DIM 256
#define H1 512
#define H2 128
#define BM 128
#define BN 128
#define BK 32
#define LDT 40   // LDS row stride in shorts (padded: 80B rows -> <=2-way bank conflict, free)
#define SCAN_CHUNK 4096  // 256 threads x 16 elements

typedef unsigned short u16;
typedef __attribute__((ext_vector_type(8))) short short8;
typedef __attribute__((ext_vector_type(4))) float floatx4;

__device__ __forceinline__ u16 f2bf(float f) {
    union { float f; unsigned u; } c; c.f = f;
    unsigned u = c.u;
    return (u16)((u + 0x7fffu + ((u >> 16) & 1u)) >> 16);
}
__device__ __forceinline__ float bflo(unsigned w) {
    union { unsigned u; float f; } c; c.u = w << 16; return c.f;
}
__device__ __forceinline__ float bfhi(unsigned w) {
    union { unsigned u; float f; } c; c.u = w & 0xffff0000u; return c.f;
}

// ---- mask bit-pack: one coalesced pass over mask1 (102 MB -> 3.2 MB) ------
// bit i of wave-ballot = lane i; output dwords are therefore in column order.

__global__ __launch_bounds__(256) void pack_mask_kernel(const int* __restrict__ mask,
        unsigned long long* __restrict__ bits, int total) {
    int gid = blockIdx.x * blockDim.x + threadIdx.x;
    int v = (gid < total) ? mask[gid] : 0;
    unsigned long long b = __ballot(v != 0);
    if ((threadIdx.x & 63) == 0 && gid < total) bits[gid >> 6] = b;
}

// ---- graph prep ----------------------------------------------------------

__global__ void hist_kernel(const int* __restrict__ dstA, int* __restrict__ counts,
                            int E, int n) {
    int e = blockIdx.x * blockDim.x + threadIdx.x;
    if (e < E) {
        int d = dstA[e];
        if ((unsigned)d < (unsigned)n) atomicAdd(&counts[d], 1);
    }
}

// 3-dispatch hierarchical exclusive scan of counts[0..n) ->
// row_start/cursor (+ dis = rsqrt(counts+1)).

__global__ __launch_bounds__(256) void partial_sum_kernel(const int* __restrict__ counts,
        int* __restrict__ partials, int n) {
    int t = threadIdx.x;
    int base = blockIdx.x * SCAN_CHUNK + t * 16;
    int s = 0;
    int m = (base < n) ? min(16, n - base) : 0;
    for (int i = 0; i < m; ++i) s += counts[base + i];
    __shared__ int red[256];
    red[t] = s;
    __syncthreads();
    for (int off = 128; off > 0; off >>= 1) {
        if (t < off) red[t] += red[t + off];
        __syncthreads();
    }
    if (t == 0) partials[blockIdx.x] = red[0];
}

__global__ void scan_partials_kernel(int* __restrict__ partials, int nb) {
    if (threadIdx.x == 0 && blockIdx.x == 0) {
        int run = 0;
        for (int i = 0; i < nb; ++i) { int c = partials[i]; partials[i] = run; run += c; }
        partials[nb] = run;   // total
    }
}

__global__ __launch_bounds__(256) void scan_emit_kernel(const int* __restrict__ counts,
        const int* __restrict__ partials, int* __restrict__ row_start,
        int* __restrict__ cursor, float* __restrict__ dis, int n, int nb) {
    int t = threadIdx.x;
    int base = blockIdx.x * SCAN_CHUNK + t * 16;
    int cnt[16];
    int s = 0;
    int m = (base < n) ? min(16, n - base) : 0;
    for (int i = 0; i < m; ++i) { cnt[i] = counts[base + i]; s += cnt[i]; }
    __shared__ int red[256];
    red[t] = s;
    __syncthreads();
    for (int off = 1; off < 256; off <<= 1) {   // inclusive Hillis-Steele
        int v = red[t];
        int vo = (t >= off) ? red[t - off] : 0;
        __syncthreads();
        red[t] = v + vo;
        __syncthreads();
    }
    int run = partials[blockIdx.x] + (t ? red[t - 1] : 0);
    for (int i = 0; i < m; ++i) {
        int c = cnt[i];
        row_start[base + i] = run;
        cursor[base + i] = run;
        dis[base + i] = rsqrtf((float)(c + 1));   // deg = indeg + self-loop
        run += c;
    }
    if (blockIdx.x == 0 && t == 0) row_start[n] = partials[nb];
}

__global__ void scatter_kernel(const int* __restrict__ srcA, const int* __restrict__ dstA,
                               int* __restrict__ cursor, int* __restrict__ csr,
                               int E, int n) {
    int e = blockIdx.x * blockDim.x + threadIdx.x;
    if (e < E) {
        int d = dstA[e];
        int s = srcA[e];
        if ((unsigned)d < (unsigned)n && (unsigned)s < (unsigned)n) {
            int p = atomicAdd(&cursor[d], 1);
            csr[p] = s;
        }
    }
}

// xs[i,:] = bf16(dis[i] * x[i,:])
__global__ void scale_cast_kernel(const float* __restrict__ x, const float* __restrict__ dis,
                                  u16* __restrict__ xs, int n) {
    int gid = blockIdx.x * blockDim.x + threadIdx.x;
    int total = n * (IN_DIM / 4);
    if (gid >= total) return;
    int node = gid >> 6;   // IN_DIM/4 == 64
    float4 v = ((const float4*)x)[gid];
    float d = dis[node];
    uint2 o;
    o.x = (unsigned)f2bf(v.x * d) | ((unsigned)f2bf(v.y * d) << 16);
    o.y = (unsigned)f2bf(v.z * d) | ((unsigned)f2bf(v.w * d) << 16);
    ((uint2*)xs)[gid] = o;
}

// Wt[c,k] = bf16(W[k,c]);  W is K x Ncols row-major
__global__ void transpose_cast_kernel(const float* __restrict__ W, u16* __restrict__ Wt,
                                      int K, int Ncols) {
    int idx = blockIdx.x * blockDim.x + threadIdx.x;
    if (idx >= K * Ncols) return;
    int k = idx / Ncols, c = idx - k * Ncols;
    Wt[c * K + k] = f2bf(W[idx]);
}

// ---- aggregation 1: aggx[d] = bf16( dis[d] * (xs[d] + sum_{s in in(d)} xs[s]) ) -----

__global__ __launch_bounds__(256) void agg1_kernel(const u16* __restrict__ xs,
        const int* __restrict__ row_start, const int* __restrict__ csr,
        const float* __restrict__ dis, u16* __restrict__ aggx, int n) {
    int gid = blockIdx.x * blockDim.x + threadIdx.x;
    int w = gid >> 6, lane = gid & 63;
    if (w >= n) return;
    const uint2* base = (const uint2*)xs;       // 64 uint2 per 256-feat row
    uint2 v = base[(size_t)w * 64 + lane];      // self-loop seed
    float a0 = bflo(v.x), a1 = bfhi(v.x), a2 = bflo(v.y), a3 = bfhi(v.y);
    int b = row_start[w], e = row_start[w + 1];
    for (int i = b; i < e; ++i) {
        int s = csr[i];
        uint2 u = base[(size_t)s * 64 + lane];
        a0 += bflo(u.x); a1 += bfhi(u.x); a2 += bflo(u.y); a3 += bfhi(u.y);
    }
    float dd = dis[w];
    uint2 o;
    o.x = (unsigned)f2bf(a0 * dd) | ((unsigned)f2bf(a1 * dd) << 16);
    o.y = (unsigned)f2bf(a2 * dd) | ((unsigned)f2bf(a3 * dd) << 16);
    ((uint2*)aggx)[(size_t)w * 64 + lane] = o;
}

// ---- GEMM1: feat1 = dropout(prelu(aggx @ W1 + b1)) -> bf16 ----------------
// A: M x 256 bf16 row-major; Bt: 512 x 256 bf16 (W1 transposed). mbits: bit-packed mask1.

__global__ __launch_bounds__(256) void gemm1_kernel(const u16* __restrict__ A,
        const u16* __restrict__ Bt, const float* __restrict__ bias,
        const float* __restrict__ a_p, const unsigned* __restrict__ mbits,
        u16* __restrict__ out, int M) {
    const int K = IN_DIM;
    __shared__ __align__(16) u16 As[BM * LDT];
    __shared__ __align__(16) u16 Bs[BN * LDT];
    int tid = threadIdx.x;
    int wave = tid >> 6, lane = tid & 63;
    int quad = lane >> 4, l16 = lane & 15;
    int wm = wave & 1, wn = wave >> 1;
    int m0 = blockIdx.x * BM, n0 = blockIdx.y * BN;

    floatx4 acc[4][4];
#pragma unroll
    for (int i = 0; i < 4; i++)
#pragma unroll
        for (int j = 0; j < 4; j++) acc[i][j] = (floatx4){0.f, 0.f, 0.f, 0.f};

    for (int k0 = 0; k0 < K; k0 += BK) {
        __syncthreads();
#pragma unroll
        for (int u = tid; u < 512; u += 256) {   // 128 rows x 4 uint4
            int row = u >> 2, seg = u & 3;
            uint4 av = make_uint4(0, 0, 0, 0);
            int gr = m0 + row;
            if (gr < M) av = *(const uint4*)&A[(size_t)gr * K + k0 + seg * 8];
            *(uint4*)&As[row * LDT + seg * 8] = av;
            uint4 bv = *(const uint4*)&Bt[(size_t)(n0 + row) * K + k0 + seg * 8];
            *(uint4*)&Bs[row * LDT + seg * 8] = bv;
        }
        __syncthreads();
        short8 af[4], bf8[4];
#pragma unroll
        for (int i = 0; i < 4; i++)
            af[i] = *(const short8*)&As[(wm * 64 + i * 16 + l16) * LDT + quad * 8];
#pragma unroll
        for (int i = 0; i < 4; i++)
            bf8[i] = *(const short8*)&Bs[(wn * 64 + i * 16 + l16) * LDT + quad * 8];
#pragma unroll
        for (int mt = 0; mt < 4; mt++)
#pragma unroll
            for (int nt = 0; nt < 4; nt++)
                acc[mt][nt] = __builtin_amdgcn_mfma_f32_16x16x32_bf16(
                    af[mt], bf8[nt], acc[mt][nt], 0, 0, 0);
    }

    // stage this block's mask bits (128 rows x 4 dwords = 2 KB) into LDS (alias As)
    unsigned* mb = (unsigned*)As;
    __syncthreads();
    for (int u = tid; u < BM * 4; u += 256) {
        int row = u >> 2, j = u & 3;
        int gr = m0 + row;
        unsigned val = 0;
        if (gr < M) val = mbits[(size_t)gr * (H1 / 32) + (n0 >> 5) + j];
        mb[u] = val;
    }
    __syncthreads();

    float alpha = a_p[0];
#pragma unroll
    for (int mt = 0; mt < 4; mt++) {
#pragma unroll
        for (int r = 0; r < 4; r++) {
            int lr = wm * 64 + mt * 16 + quad * 4 + r;   // local row in [0,128)
            int row = m0 + lr;
            if (row >= M) continue;
#pragma unroll
            for (int nt = 0; nt < 4; nt++) {
                int c64 = nt * 16 + l16;                 // col within wn's 64-col half
                int col = n0 + wn * 64 + c64;
                float v = acc[mt][nt][r] + bias[col];
                v = (v >= 0.f) ? v : alpha * v;
                unsigned bits = mb[lr * 4 + wn * 2 + (c64 >> 5)];  // quad-broadcast, conflict-free
                v = (bits >> (c64 & 31)) & 1u ? v * 2.0f : 0.0f;
                out[(size_t)row * H1 + col] = f2bf(v);
            }
        }
    }
}

// ---- GEMM2: ts = bf16( dis[row] * (feat1 @ W2) ) --------------------------
// A: M x 512 bf16; Bt: 128 x 512 bf16

__global__ __launch_bounds__(256) void gemm2_kernel(const u16* __restrict__ A,
        const u16* __restrict__ Bt, const float* __restrict__ dis,
        u16* __restrict__ out, int M) {
    const int K = H1;
    __shared__ __align__(16) u16 As[BM * LDT];
    __shared__ __align__(16) u16 Bs[BN * LDT];
    int tid = threadIdx.x;
    int wave = tid >> 6, lane = tid & 63;
    int quad = lane >> 4, l16 = lane & 15;
    int wm = wave & 1, wn = wave >> 1;
    int m0 = blockIdx.x * BM, n0 = 0;

    floatx4 acc[4][4];
#pragma unroll
    for (int i = 0; i < 4; i++)
#pragma unroll
        for (int j = 0; j < 4; j++) acc[i][j] = (floatx4){0.f, 0.f, 0.f, 0.f};

    for (int k0 = 0; k0 < K; k0 += BK) {
        __syncthreads();
#pragma unroll
        for (int u = tid; u < 512; u += 256) {
            int row = u >> 2, seg = u & 3;
            uint4 av = make_uint4(0, 0, 0, 0);
            int gr = m0 + row;
            if (gr < M) av = *(const uint4*)&A[(size_t)gr * K + k0 + seg * 8];
            *(uint4*)&As[row * LDT + seg * 8] = av;
            uint4 bv = *(const uint4*)&Bt[(size_t)(n0 + row) * K + k0 + seg * 8];
            *(uint4*)&Bs[row * LDT + seg * 8] = bv;
        }
        __syncthreads();
        short8 af[4], bf8[4];
#pragma unroll
        for (int i = 0; i < 4; i++)
            af[i] = *(const short8*)&As[(wm * 64 + i * 16 + l16) * LDT + quad * 8];
#pragma unroll
        for (int i = 0; i < 4; i++)
            bf8[i] = *(const short8*)&Bs[(wn * 64 + i * 16 + l16) * LDT + quad * 8];
#pragma unroll
        for (int mt = 0; mt < 4; mt++)
#pragma unroll
            for (int nt = 0; nt < 4; nt++)
                acc[mt][nt] = __builtin_amdgcn_mfma_f32_16x16x32_bf16(
                    af[mt], bf8[nt], acc[mt][nt], 0, 0, 0);
    }

#pragma unroll
    for (int mt = 0; mt < 4; mt++) {
#pragma unroll
        for (int r = 0; r < 4; r++) {
            int row = m0 + wm * 64 + mt * 16 + quad * 4 + r;
            if (row >= M) continue;
            float dd = dis[row];
#pragma unroll
            for (int nt = 0; nt < 4; nt++) {
                int col = n0 + wn * 64 + nt * 16 + l16;
                out[(size_t)row * H2 + col] = f2bf(acc[mt][nt][r] * dd);
            }
        }
    }
}

// ---- aggregation 2 + epilogue: out = dropout(prelu(dis[d]*(ts[d]+sum ts[s]) + b2)) --

__global__ __launch_bounds__(256) void agg2_kernel(const u16* __restrict__ ts,
        const int* __restrict__ row_start, const int* __restrict__ csr,
        const float* __restrict__ dis, const float* __restrict__ b2,
        const float* __restrict__ a_p, const int* __restrict__ mask,
        float* __restrict__ out, int n) {
    int gid = blockIdx.x * blockDim.x + threadIdx.x;
    int w = gid >> 6, lane = gid & 63;
    if (w >= n) return;
    const unsigned* base = (const unsigned*)ts;   // 64 uints per 128-feat row
    unsigned v = base[(size_t)w * 64 + lane];
    float a0 = bflo(v), a1 = bfhi(v);
    int b = row_start[w], e = row_start[w + 1];
    for (int i = b; i < e; ++i) {
        int s = csr[i];
        unsigned u = base[(size_t)s * 64 + lane];
        a0 += bflo(u); a1 += bfhi(u);
    }
    float dd = dis[w];
    float alpha = a_p[0];
    int c0 = lane * 2;
    float v0 = dd * a0 + b2[c0];
    float v1 = dd * a1 + b2[c0 + 1];
    v0 = (v0 >= 0.f) ? v0 : alpha * v0;
    v1 = (v1 >= 0.f) ? v1 : alpha * v1;
    int2 m = ((const int2*)mask)[(size_t)w * 64 + lane];
    v0 = m.x ? v0 * 2.f : 0.f;
    v1 = m.y ? v1 * 2.f : 0.f;
    ((float2*)out)[(size_t)w * 64 + lane] = make_float2(v0, v1);
}

// ---- launch ---------------------------------------------------------------

extern "C" void kernel_launch(void* const* d_in, const int* in_sizes, int n_in,
                              void* d_out, int out_size, void* d_ws, size_t ws_size,
                              hipStream_t stream) {
    const float* x  = (const float*)d_in[0];
    const int* ei   = (const int*)d_in[1];
    const float* W1 = (const float*)d_in[2];
    const float* b1 = (const float*)d_in[3];
    const float* W2 = (const float*)d_in[4];
    const float* b2 = (const float*)d_in[5];
    const float* ap = (const float*)d_in[6];
    const int* mask1 = (const int*)d_in[7];
    const int* mask2 = (const int*)d_in[8];

    int n = in_sizes[0] / IN_DIM;      // 50000
    int E = in_sizes[1] / 2;           // 400000
    const int* srcA = ei;
    const int* dstA = ei + E;

    // ws layout (aliased lifetimes, ~64 MiB total):
    //   feat1 (n*H1 bf16); first half doubles as xs before gemm1 writes feat1
    //   ts (doubles as mask1 bitpack before gemm2 writes ts), w1t, w2t,
    //   dis, counts, cursor, row_start, csr, partials
    // aggx (n*IN_DIM bf16) lives in d_out (dead before agg2 rewrites d_out).
    char* p = (char*)d_ws;
    auto alloc = [&](size_t bytes) {
        char* r = p;
        p += (bytes + 255) & ~(size_t)255;
        return r;
    };
    u16* feat1     = (u16*)alloc((size_t)n * H1 * 2);
    u16* xs        = feat1;            // alias: xs dead before feat1 is written
    u16* ts        = (u16*)alloc((size_t)n * H2 * 2);
    unsigned* bits1 = (unsigned*)ts;   // alias: bits1 dead before gemm2 writes ts
    u16* w1t       = (u16*)alloc((size_t)IN_DIM * H1 * 2);
    u16* w2t       = (u16*)alloc((size_t)H1 * H2 * 2);
    float* dis     = (float*)alloc((size_t)n * 4);
    int* counts    = (int*)alloc((size_t)n * 4);
    int* cursor    = (int*)alloc((size_t)n * 4);
    int* row_start = (int*)alloc(((size_t)n + 1) * 4);
    int* csr       = (int*)alloc((size_t)E * 4);
    int nscan = (n + SCAN_CHUNK - 1) / SCAN_CHUNK;
    int* partials  = (int*)alloc(((size_t)nscan + 1) * 4);
    u16* aggx      = (u16*)d_out;      // n*IN_DIM*2 == out_size*4 bytes exactly
    if ((size_t)(p - (char*)d_ws) > ws_size) return;  // ws too small: leave zeros

    const int tpb = 256;
    int total_m1 = n * H1;             // divisible by 64
    hipMemsetAsync(counts, 0, (size_t)n * 4, stream);
    pack_mask_kernel<<<(total_m1 + tpb - 1) / tpb, tpb, 0, stream>>>(mask1,
        (unsigned long long*)bits1, total_m1);
    hist_kernel<<<(E + tpb - 1) / tpb, tpb, 0, stream>>>(dstA, counts, E, n);
    partial_sum_kernel<<<nscan, tpb, 0, stream>>>(counts, partials, n);
    scan_partials_kernel<<<1, 64, 0, stream>>>(partials, nscan);
    scan_emit_kernel<<<nscan, tpb, 0, stream>>>(counts, partials, row_start, cursor, dis, n, nscan);
    scatter_kernel<<<(E + tpb - 1) / tpb, tpb, 0, stream>>>(srcA, dstA, cursor, csr, E, n);
    scale_cast_kernel<<<((n * (IN_DIM / 4)) + tpb - 1) / tpb, tpb, 0, stream>>>(x, dis, xs, n);
    transpose_cast_kernel<<<((IN_DIM * H1) + tpb - 1) / tpb, tpb, 0, stream>>>(W1, w1t, IN_DIM, H1);
    transpose_cast_kernel<<<((H1 * H2) + tpb - 1) / tpb, tpb, 0, stream>>>(W2, w2t, H1, H2);
    agg1_kernel<<<(n * 64 + tpb - 1) / tpb, tpb, 0, stream>>>(xs, row_start, csr, dis, aggx, n);
    dim3 g1((n + BM - 1) / BM, H1 / BN);
    gemm1_kernel<<<g1, tpb, 0, stream>>>(aggx, w1t, b1, ap, bits1, feat1, n);
    dim3 g2((n + BM - 1) / BM, 1);
    gemm2_kernel<<<g2, tpb, 0, stream>>>(feat1, w2t, dis, ts, n);
    agg2_kernel<<<(n * 64 + tpb - 1) / tpb, tpb, 0, stream>>>(ts, row_start, csr, dis, b2, ap,
                                                              mask2, (float*)d_out, n);
}

// Round 5
// 454.024 us; speedup vs baseline: 1.0510x; 1.0510x over previous
//
#include <hip/hip_runtime.h>
#include <hip/hip_bf16.h>

#define IN_DIM 256
#define H1 512
#define H2 128
#define BM 128
#define BN 128
#define BK 32
#define LDT 40   // LDS row stride in shorts (padded: 80B rows -> <=2-way bank conflict, free)
#define SCAN_CHUNK 4096  // 256 threads x 16 elements

typedef unsigned short u16;
typedef unsigned long long u64;
typedef __attribute__((ext_vector_type(8))) short short8;
typedef __attribute__((ext_vector_type(4))) float floatx4;

__device__ __forceinline__ u16 f2bf(float f) {
    union { float f; unsigned u; } c; c.f = f;
    unsigned u = c.u;
    return (u16)((u + 0x7fffu + ((u >> 16) & 1u)) >> 16);
}
__device__ __forceinline__ float bflo(unsigned w) {
    union { unsigned u; float f; } c; c.u = w << 16; return c.f;
}
__device__ __forceinline__ float bfhi(unsigned w) {
    union { unsigned u; float f; } c; c.u = w & 0xffff0000u; return c.f;
}

// ---- mask bit-pack: int4 per thread (16B/lane), 4 ballots per wave --------
// Layout: bit i of word [g*4+j] = mask[g*256 + 4*i + j]  (g = wave index).
// Consumer remaps: for flat f, word = (f>>8)*4 + (f&3), bit = (f>>2)&63.

__global__ __launch_bounds__(256) void pack_mask_kernel(const int4* __restrict__ mask4,
        u64* __restrict__ bits, int total4) {
    int gid = blockIdx.x * blockDim.x + threadIdx.x;
    int lane = threadIdx.x & 63;
    int4 v = (gid < total4) ? mask4[gid] : make_int4(0, 0, 0, 0);
    u64 b0 = __ballot(v.x != 0);
    u64 b1 = __ballot(v.y != 0);
    u64 b2 = __ballot(v.z != 0);
    u64 b3 = __ballot(v.w != 0);
    u64 sel = (lane == 0) ? b0 : (lane == 1) ? b1 : (lane == 2) ? b2 : b3;
    if (lane < 4 && gid < total4)
        bits[(size_t)(gid >> 6) * 4 + lane] = sel;
}

// ---- graph prep ----------------------------------------------------------

__global__ void hist_kernel(const int* __restrict__ dstA, int* __restrict__ counts,
                            int E, int n) {
    int e = blockIdx.x * blockDim.x + threadIdx.x;
    if (e < E) {
        int d = dstA[e];
        if ((unsigned)d < (unsigned)n) atomicAdd(&counts[d], 1);
    }
}

// 3-dispatch hierarchical exclusive scan of counts[0..n) ->
// row_start/cursor (+ dis = rsqrt(counts+1)).

__global__ __launch_bounds__(256) void partial_sum_kernel(const int* __restrict__ counts,
        int* __restrict__ partials, int n) {
    int t = threadIdx.x;
    int base = blockIdx.x * SCAN_CHUNK + t * 16;
    int s = 0;
    int m = (base < n) ? min(16, n - base) : 0;
    for (int i = 0; i < m; ++i) s += counts[base + i];
    __shared__ int red[256];
    red[t] = s;
    __syncthreads();
    for (int off = 128; off > 0; off >>= 1) {
        if (t < off) red[t] += red[t + off];
        __syncthreads();
    }
    if (t == 0) partials[blockIdx.x] = red[0];
}

__global__ void scan_partials_kernel(int* __restrict__ partials, int nb) {
    if (threadIdx.x == 0 && blockIdx.x == 0) {
        int run = 0;
        for (int i = 0; i < nb; ++i) { int c = partials[i]; partials[i] = run; run += c; }
        partials[nb] = run;   // total
    }
}

__global__ __launch_bounds__(256) void scan_emit_kernel(const int* __restrict__ counts,
        const int* __restrict__ partials, int* __restrict__ row_start,
        int* __restrict__ cursor, float* __restrict__ dis, int n, int nb) {
    int t = threadIdx.x;
    int base = blockIdx.x * SCAN_CHUNK + t * 16;
    int cnt[16];
    int s = 0;
    int m = (base < n) ? min(16, n - base) : 0;
    for (int i = 0; i < m; ++i) { cnt[i] = counts[base + i]; s += cnt[i]; }
    __shared__ int red[256];
    red[t] = s;
    __syncthreads();
    for (int off = 1; off < 256; off <<= 1) {   // inclusive Hillis-Steele
        int v = red[t];
        int vo = (t >= off) ? red[t - off] : 0;
        __syncthreads();
        red[t] = v + vo;
        __syncthreads();
    }
    int run = partials[blockIdx.x] + (t ? red[t - 1] : 0);
    for (int i = 0; i < m; ++i) {
        int c = cnt[i];
        row_start[base + i] = run;
        cursor[base + i] = run;
        dis[base + i] = rsqrtf((float)(c + 1));   // deg = indeg + self-loop
        run += c;
    }
    if (blockIdx.x == 0 && t == 0) row_start[n] = partials[nb];
}

__global__ void scatter_kernel(const int* __restrict__ srcA, const int* __restrict__ dstA,
                               int* __restrict__ cursor, int* __restrict__ csr,
                               int E, int n) {
    int e = blockIdx.x * blockDim.x + threadIdx.x;
    if (e < E) {
        int d = dstA[e];
        int s = srcA[e];
        if ((unsigned)d < (unsigned)n && (unsigned)s < (unsigned)n) {
            int p = atomicAdd(&cursor[d], 1);
            csr[p] = s;
        }
    }
}

// xs[i,:] = bf16(dis[i] * x[i,:])
__global__ void scale_cast_kernel(const float* __restrict__ x, const float* __restrict__ dis,
                                  u16* __restrict__ xs, int n) {
    int gid = blockIdx.x * blockDim.x + threadIdx.x;
    int total = n * (IN_DIM / 4);
    if (gid >= total) return;
    int node = gid >> 6;   // IN_DIM/4 == 64
    float4 v = ((const float4*)x)[gid];
    float d = dis[node];
    uint2 o;
    o.x = (unsigned)f2bf(v.x * d) | ((unsigned)f2bf(v.y * d) << 16);
    o.y = (unsigned)f2bf(v.z * d) | ((unsigned)f2bf(v.w * d) << 16);
    ((uint2*)xs)[gid] = o;
}

// Wt[c,k] = bf16(W[k,c]);  W is K x Ncols row-major
__global__ void transpose_cast_kernel(const float* __restrict__ W, u16* __restrict__ Wt,
                                      int K, int Ncols) {
    int idx = blockIdx.x * blockDim.x + threadIdx.x;
    if (idx >= K * Ncols) return;
    int k = idx / Ncols, c = idx - k * Ncols;
    Wt[c * K + k] = f2bf(W[idx]);
}

// ---- aggregation 1: aggx[d] = bf16( dis[d] * (xs[d] + sum_{s in in(d)} xs[s]) ) -----

__global__ __launch_bounds__(256) void agg1_kernel(const u16* __restrict__ xs,
        const int* __restrict__ row_start, const int* __restrict__ csr,
        const float* __restrict__ dis, u16* __restrict__ aggx, int n) {
    int gid = blockIdx.x * blockDim.x + threadIdx.x;
    int w = gid >> 6, lane = gid & 63;
    if (w >= n) return;
    const uint2* base = (const uint2*)xs;       // 64 uint2 per 256-feat row
    uint2 v = base[(size_t)w * 64 + lane];      // self-loop seed
    float a0 = bflo(v.x), a1 = bfhi(v.x), a2 = bflo(v.y), a3 = bfhi(v.y);
    int b = row_start[w], e = row_start[w + 1];
    for (int i = b; i < e; ++i) {
        int s = csr[i];
        uint2 u = base[(size_t)s * 64 + lane];
        a0 += bflo(u.x); a1 += bfhi(u.x); a2 += bflo(u.y); a3 += bfhi(u.y);
    }
    float dd = dis[w];
    uint2 o;
    o.x = (unsigned)f2bf(a0 * dd) | ((unsigned)f2bf(a1 * dd) << 16);
    o.y = (unsigned)f2bf(a2 * dd) | ((unsigned)f2bf(a3 * dd) << 16);
    ((uint2*)aggx)[(size_t)w * 64 + lane] = o;
}

// ---- GEMM1: feat1 = dropout(prelu(aggx @ W1 + b1)) -> bf16 ----------------
// A: M x 256 bf16 row-major; Bt: 512 x 256 bf16 (W1 transposed).
// mbits: bit-packed mask1 in pack_mask layout (8 u64 per row of 512).

__global__ __launch_bounds__(256) void gemm1_kernel(const u16* __restrict__ A,
        const u16* __restrict__ Bt, const float* __restrict__ bias,
        const float* __restrict__ a_p, const u64* __restrict__ mbits,
        u16* __restrict__ out, int M) {
    const int K = IN_DIM;
    __shared__ __align__(16) u16 As[BM * LDT];
    __shared__ __align__(16) u16 Bs[BN * LDT];
    int tid = threadIdx.x;
    int wave = tid >> 6, lane = tid & 63;
    int quad = lane >> 4, l16 = lane & 15;
    int wm = wave & 1, wn = wave >> 1;
    int m0 = blockIdx.x * BM, n0 = blockIdx.y * BN;

    floatx4 acc[4][4];
#pragma unroll
    for (int i = 0; i < 4; i++)
#pragma unroll
        for (int j = 0; j < 4; j++) acc[i][j] = (floatx4){0.f, 0.f, 0.f, 0.f};

    for (int k0 = 0; k0 < K; k0 += BK) {
        __syncthreads();
#pragma unroll
        for (int u = tid; u < 512; u += 256) {   // 128 rows x 4 uint4
            int row = u >> 2, seg = u & 3;
            uint4 av = make_uint4(0, 0, 0, 0);
            int gr = m0 + row;
            if (gr < M) av = *(const uint4*)&A[(size_t)gr * K + k0 + seg * 8];
            *(uint4*)&As[row * LDT + seg * 8] = av;
            uint4 bv = *(const uint4*)&Bt[(size_t)(n0 + row) * K + k0 + seg * 8];
            *(uint4*)&Bs[row * LDT + seg * 8] = bv;
        }
        __syncthreads();
        short8 af[4], bf8[4];
#pragma unroll
        for (int i = 0; i < 4; i++)
            af[i] = *(const short8*)&As[(wm * 64 + i * 16 + l16) * LDT + quad * 8];
#pragma unroll
        for (int i = 0; i < 4; i++)
            bf8[i] = *(const short8*)&Bs[(wn * 64 + i * 16 + l16) * LDT + quad * 8];
#pragma unroll
        for (int mt = 0; mt < 4; mt++)
#pragma unroll
            for (int nt = 0; nt < 4; nt++)
                acc[mt][nt] = __builtin_amdgcn_mfma_f32_16x16x32_bf16(
                    af[mt], bf8[nt], acc[mt][nt], 0, 0, 0);
    }

    // stage this block's mask bits (128 rows x 4 u64, stride 5 -> 5KB, alias As)
    u64* mb = (u64*)As;
    __syncthreads();
    for (int u = tid; u < BM * 4; u += 256) {
        int row = u >> 2, j = u & 3;
        int gr = m0 + row;
        u64 val = 0;
        if (gr < M) val = mbits[(size_t)gr * 8 + (n0 >> 8) * 4 + j];
        mb[row * 5 + j] = val;   // stride 5: quad x j pattern hits 16 distinct bank-pairs
    }
    __syncthreads();

    float alpha = a_p[0];
#pragma unroll
    for (int mt = 0; mt < 4; mt++) {
#pragma unroll
        for (int r = 0; r < 4; r++) {
            int lr = wm * 64 + mt * 16 + quad * 4 + r;   // local row in [0,128)
            int row = m0 + lr;
            if (row >= M) continue;
#pragma unroll
            for (int nt = 0; nt < 4; nt++) {
                int c64 = nt * 16 + l16;                 // col within wn's 64-col half
                int col = n0 + wn * 64 + c64;
                float v = acc[mt][nt][r] + bias[col];
                v = (v >= 0.f) ? v : alpha * v;
                u64 w = mb[lr * 5 + (l16 & 3)];          // j = col & 3 == l16 & 3
                int bit = ((n0 >> 2) + wn * 16 + nt * 4 + (l16 >> 2)) & 63;  // (col>>2)&63
                v = ((w >> bit) & 1ull) ? v * 2.0f : 0.0f;
                out[(size_t)row * H1 + col] = f2bf(v);
            }
        }
    }
}

// ---- GEMM2: ts = bf16( dis[row] * (feat1 @ W2) ) --------------------------
// A: M x 512 bf16; Bt: 128 x 512 bf16

__global__ __launch_bounds__(256) void gemm2_kernel(const u16* __restrict__ A,
        const u16* __restrict__ Bt, const float* __restrict__ dis,
        u16* __restrict__ out, int M) {
    const int K = H1;
    __shared__ __align__(16) u16 As[BM * LDT];
    __shared__ __align__(16) u16 Bs[BN * LDT];
    int tid = threadIdx.x;
    int wave = tid >> 6, lane = tid & 63;
    int quad = lane >> 4, l16 = lane & 15;
    int wm = wave & 1, wn = wave >> 1;
    int m0 = blockIdx.x * BM, n0 = 0;

    floatx4 acc[4][4];
#pragma unroll
    for (int i = 0; i < 4; i++)
#pragma unroll
        for (int j = 0; j < 4; j++) acc[i][j] = (floatx4){0.f, 0.f, 0.f, 0.f};

    for (int k0 = 0; k0 < K; k0 += BK) {
        __syncthreads();
#pragma unroll
        for (int u = tid; u < 512; u += 256) {
            int row = u >> 2, seg = u & 3;
            uint4 av = make_uint4(0, 0, 0, 0);
            int gr = m0 + row;
            if (gr < M) av = *(const uint4*)&A[(size_t)gr * K + k0 + seg * 8];
            *(uint4*)&As[row * LDT + seg * 8] = av;
            uint4 bv = *(const uint4*)&Bt[(size_t)(n0 + row) * K + k0 + seg * 8];
            *(uint4*)&Bs[row * LDT + seg * 8] = bv;
        }
        __syncthreads();
        short8 af[4], bf8[4];
#pragma unroll
        for (int i = 0; i < 4; i++)
            af[i] = *(const short8*)&As[(wm * 64 + i * 16 + l16) * LDT + quad * 8];
#pragma unroll
        for (int i = 0; i < 4; i++)
            bf8[i] = *(const short8*)&Bs[(wn * 64 + i * 16 + l16) * LDT + quad * 8];
#pragma unroll
        for (int mt = 0; mt < 4; mt++)
#pragma unroll
            for (int nt = 0; nt < 4; nt++)
                acc[mt][nt] = __builtin_amdgcn_mfma_f32_16x16x32_bf16(
                    af[mt], bf8[nt], acc[mt][nt], 0, 0, 0);
    }

#pragma unroll
    for (int mt = 0; mt < 4; mt++) {
#pragma unroll
        for (int r = 0; r < 4; r++) {
            int row = m0 + wm * 64 + mt * 16 + quad * 4 + r;
            if (row >= M) continue;
            float dd = dis[row];
#pragma unroll
            for (int nt = 0; nt < 4; nt++) {
                int col = n0 + wn * 64 + nt * 16 + l16;
                out[(size_t)row * H2 + col] = f2bf(acc[mt][nt][r] * dd);
            }
        }
    }
}

// ---- aggregation 2 + epilogue: out = dropout(prelu(dis[d]*(ts[d]+sum ts[s]) + b2)) --

__global__ __launch_bounds__(256) void agg2_kernel(const u16* __restrict__ ts,
        const int* __restrict__ row_start, const int* __restrict__ csr,
        const float* __restrict__ dis, const float* __restrict__ b2,
        const float* __restrict__ a_p, const int* __restrict__ mask,
        float* __restrict__ out, int n) {
    int gid = blockIdx.x * blockDim.x + threadIdx.x;
    int w = gid >> 6, lane = gid & 63;
    if (w >= n) return;
    const unsigned* base = (const unsigned*)ts;   // 64 uints per 128-feat row
    unsigned v = base[(size_t)w * 64 + lane];
    float a0 = bflo(v), a1 = bfhi(v);
    int b = row_start[w], e = row_start[w + 1];
    for (int i = b; i < e; ++i) {
        int s = csr[i];
        unsigned u = base[(size_t)s * 64 + lane];
        a0 += bflo(u); a1 += bfhi(u);
    }
    float dd = dis[w];
    float alpha = a_p[0];
    int c0 = lane * 2;
    float v0 = dd * a0 + b2[c0];
    float v1 = dd * a1 + b2[c0 + 1];
    v0 = (v0 >= 0.f) ? v0 : alpha * v0;
    v1 = (v1 >= 0.f) ? v1 : alpha * v1;
    int2 m = ((const int2*)mask)[(size_t)w * 64 + lane];
    v0 = m.x ? v0 * 2.f : 0.f;
    v1 = m.y ? v1 * 2.f : 0.f;
    ((float2*)out)[(size_t)w * 64 + lane] = make_float2(v0, v1);
}

// ---- launch ---------------------------------------------------------------

extern "C" void kernel_launch(void* const* d_in, const int* in_sizes, int n_in,
                              void* d_out, int out_size, void* d_ws, size_t ws_size,
                              hipStream_t stream) {
    const float* x  = (const float*)d_in[0];
    const int* ei   = (const int*)d_in[1];
    const float* W1 = (const float*)d_in[2];
    const float* b1 = (const float*)d_in[3];
    const float* W2 = (const float*)d_in[4];
    const float* b2 = (const float*)d_in[5];
    const float* ap = (const float*)d_in[6];
    const int* mask1 = (const int*)d_in[7];
    const int* mask2 = (const int*)d_in[8];

    int n = in_sizes[0] / IN_DIM;      // 50000
    int E = in_sizes[1] / 2;           // 400000
    const int* srcA = ei;
    const int* dstA = ei + E;

    // ws layout (aliased lifetimes, ~64 MiB total):
    //   feat1 (n*H1 bf16); first half doubles as xs before gemm1 writes feat1
    //   ts (doubles as mask1 bitpack before gemm2 writes ts), w1t, w2t,
    //   dis, counts, cursor, row_start, csr, partials
    // aggx (n*IN_DIM bf16) lives in d_out (dead before agg2 rewrites d_out).
    char* p = (char*)d_ws;
    auto alloc = [&](size_t bytes) {
        char* r = p;
        p += (bytes + 255) & ~(size_t)255;
        return r;
    };
    u16* feat1     = (u16*)alloc((size_t)n * H1 * 2);
    u16* xs        = feat1;            // alias: xs dead before feat1 is written
    u16* ts        = (u16*)alloc((size_t)n * H2 * 2);
    u64* bits1     = (u64*)ts;         // alias: bits1 dead before gemm2 writes ts
    u16* w1t       = (u16*)alloc((size_t)IN_DIM * H1 * 2);
    u16* w2t       = (u16*)alloc((size_t)H1 * H2 * 2);
    float* dis     = (float*)alloc((size_t)n * 4);
    int* counts    = (int*)alloc((size_t)n * 4);
    int* cursor    = (int*)alloc((size_t)n * 4);
    int* row_start = (int*)alloc(((size_t)n + 1) * 4);
    int* csr       = (int*)alloc((size_t)E * 4);
    int nscan = (n + SCAN_CHUNK - 1) / SCAN_CHUNK;
    int* partials  = (int*)alloc(((size_t)nscan + 1) * 4);
    u16* aggx      = (u16*)d_out;      // n*IN_DIM*2 == out_size*4 bytes exactly
    if ((size_t)(p - (char*)d_ws) > ws_size) return;  // ws too small: leave zeros

    const int tpb = 256;
    int total4 = n * H1 / 4;           // int4 elements; divisible by 256
    hipMemsetAsync(counts, 0, (size_t)n * 4, stream);
    pack_mask_kernel<<<(total4 + tpb - 1) / tpb, tpb, 0, stream>>>((const int4*)mask1,
        bits1, total4);
    hist_kernel<<<(E + tpb - 1) / tpb, tpb, 0, stream>>>(dstA, counts, E, n);
    partial_sum_kernel<<<nscan, tpb, 0, stream>>>(counts, partials, n);
    scan_partials_kernel<<<1, 64, 0, stream>>>(partials, nscan);
    scan_emit_kernel<<<nscan, tpb, 0, stream>>>(counts, partials, row_start, cursor, dis, n, nscan);
    scatter_kernel<<<(E + tpb - 1) / tpb, tpb, 0, stream>>>(srcA, dstA, cursor, csr, E, n);
    scale_cast_kernel<<<((n * (IN_DIM / 4)) + tpb - 1) / tpb, tpb, 0, stream>>>(x, dis, xs, n);
    transpose_cast_kernel<<<((IN_DIM * H1) + tpb - 1) / tpb, tpb, 0, stream>>>(W1, w1t, IN_DIM, H1);
    transpose_cast_kernel<<<((H1 * H2) + tpb - 1) / tpb, tpb, 0, stream>>>(W2, w2t, H1, H2);
    agg1_kernel<<<(n * 64 + tpb - 1) / tpb, tpb, 0, stream>>>(xs, row_start, csr, dis, aggx, n);
    dim3 g1((n + BM - 1) / BM, H1 / BN);
    gemm1_kernel<<<g1, tpb, 0, stream>>>(aggx, w1t, b1, ap, bits1, feat1, n);
    dim3 g2((n + BM - 1) / BM, 1);
    gemm2_kernel<<<g2, tpb, 0, stream>>>(feat1, w2t, dis, ts, n);
    agg2_kernel<<<(n * 64 + tpb - 1) / tpb, tpb, 0, stream>>>(ts, row_start, csr, dis, b2, ap,
                                                              mask2, (float*)d_out, n);
}

// Round 6
// 414.753 us; speedup vs baseline: 1.1505x; 1.0947x over previous
//
#include <hip/hip_runtime.h>
#include <hip/hip_bf16.h>

#define IN_DIM 256
#define H1 512
#define H2 128
#define BM 128
#define BN 128
#define BK 32
#define LDT 40   // LDS row stride in shorts (padded: 80B rows -> <=2-way bank conflict, free)
#define SCAN_CHUNK 4096  // 256 threads x 16 elements

typedef unsigned short u16;
typedef unsigned long long u64;
typedef __attribute__((ext_vector_type(8))) short short8;
typedef __attribute__((ext_vector_type(4))) float floatx4;

__device__ __forceinline__ u16 f2bf(float f) {
    union { float f; unsigned u; } c; c.f = f;
    unsigned u = c.u;
    return (u16)((u + 0x7fffu + ((u >> 16) & 1u)) >> 16);
}
__device__ __forceinline__ float bflo(unsigned w) {
    union { unsigned u; float f; } c; c.u = w << 16; return c.f;
}
__device__ __forceinline__ float bfhi(unsigned w) {
    union { unsigned u; float f; } c; c.u = w & 0xffff0000u; return c.f;
}

// ---- mask bit-pack: int4 per thread (16B/lane), 4 ballots per wave --------
// Layout: bit i of word [g*4+j] = mask[g*256 + 4*i + j]  (g = wave index).

__global__ __launch_bounds__(256) void pack_mask_kernel(const int4* __restrict__ mask4,
        u64* __restrict__ bits, int total4) {
    int gid = blockIdx.x * blockDim.x + threadIdx.x;
    int lane = threadIdx.x & 63;
    int4 v = (gid < total4) ? mask4[gid] : make_int4(0, 0, 0, 0);
    u64 b0 = __ballot(v.x != 0);
    u64 b1 = __ballot(v.y != 0);
    u64 b2 = __ballot(v.z != 0);
    u64 b3 = __ballot(v.w != 0);
    u64 sel = (lane == 0) ? b0 : (lane == 1) ? b1 : (lane == 2) ? b2 : b3;
    if (lane < 4 && gid < total4)
        bits[(size_t)(gid >> 6) * 4 + lane] = sel;
}

// ---- graph prep ----------------------------------------------------------

__global__ void hist_kernel(const int* __restrict__ dstA, int* __restrict__ counts,
                            int E, int n) {
    int e = blockIdx.x * blockDim.x + threadIdx.x;
    if (e < E) {
        int d = dstA[e];
        if ((unsigned)d < (unsigned)n) atomicAdd(&counts[d], 1);
    }
}

// 3-dispatch hierarchical exclusive scan of counts[0..n) ->
// row_start/cursor (+ dis = rsqrt(counts+1)).

__global__ __launch_bounds__(256) void partial_sum_kernel(const int* __restrict__ counts,
        int* __restrict__ partials, int n) {
    int t = threadIdx.x;
    int base = blockIdx.x * SCAN_CHUNK + t * 16;
    int s = 0;
    int m = (base < n) ? min(16, n - base) : 0;
    for (int i = 0; i < m; ++i) s += counts[base + i];
    __shared__ int red[256];
    red[t] = s;
    __syncthreads();
    for (int off = 128; off > 0; off >>= 1) {
        if (t < off) red[t] += red[t + off];
        __syncthreads();
    }
    if (t == 0) partials[blockIdx.x] = red[0];
}

__global__ void scan_partials_kernel(int* __restrict__ partials, int nb) {
    if (threadIdx.x == 0 && blockIdx.x == 0) {
        int run = 0;
        for (int i = 0; i < nb; ++i) { int c = partials[i]; partials[i] = run; run += c; }
        partials[nb] = run;   // total
    }
}

__global__ __launch_bounds__(256) void scan_emit_kernel(const int* __restrict__ counts,
        const int* __restrict__ partials, int* __restrict__ row_start,
        int* __restrict__ cursor, float* __restrict__ dis, int n, int nb) {
    int t = threadIdx.x;
    int base = blockIdx.x * SCAN_CHUNK + t * 16;
    int cnt[16];
    int s = 0;
    int m = (base < n) ? min(16, n - base) : 0;
    for (int i = 0; i < m; ++i) { cnt[i] = counts[base + i]; s += cnt[i]; }
    __shared__ int red[256];
    red[t] = s;
    __syncthreads();
    for (int off = 1; off < 256; off <<= 1) {   // inclusive Hillis-Steele
        int v = red[t];
        int vo = (t >= off) ? red[t - off] : 0;
        __syncthreads();
        red[t] = v + vo;
        __syncthreads();
    }
    int run = partials[blockIdx.x] + (t ? red[t - 1] : 0);
    for (int i = 0; i < m; ++i) {
        int c = cnt[i];
        row_start[base + i] = run;
        cursor[base + i] = run;
        dis[base + i] = rsqrtf((float)(c + 1));   // deg = indeg + self-loop
        run += c;
    }
    if (blockIdx.x == 0 && t == 0) row_start[n] = partials[nb];
}

__global__ void scatter_kernel(const int* __restrict__ srcA, const int* __restrict__ dstA,
                               int* __restrict__ cursor, int* __restrict__ csr,
                               int E, int n) {
    int e = blockIdx.x * blockDim.x + threadIdx.x;
    if (e < E) {
        int d = dstA[e];
        int s = srcA[e];
        if ((unsigned)d < (unsigned)n && (unsigned)s < (unsigned)n) {
            int p = atomicAdd(&cursor[d], 1);
            csr[p] = s;
        }
    }
}

// xs[i,:] = bf16(dis[i] * x[i,:])
__global__ void scale_cast_kernel(const float* __restrict__ x, const float* __restrict__ dis,
                                  u16* __restrict__ xs, int n) {
    int gid = blockIdx.x * blockDim.x + threadIdx.x;
    int total = n * (IN_DIM / 4);
    if (gid >= total) return;
    int node = gid >> 6;   // IN_DIM/4 == 64
    float4 v = ((const float4*)x)[gid];
    float d = dis[node];
    uint2 o;
    o.x = (unsigned)f2bf(v.x * d) | ((unsigned)f2bf(v.y * d) << 16);
    o.y = (unsigned)f2bf(v.z * d) | ((unsigned)f2bf(v.w * d) << 16);
    ((uint2*)xs)[gid] = o;
}

// Wt[c,k] = bf16(W[k,c]);  W is K x Ncols row-major
__global__ void transpose_cast_kernel(const float* __restrict__ W, u16* __restrict__ Wt,
                                      int K, int Ncols) {
    int idx = blockIdx.x * blockDim.x + threadIdx.x;
    if (idx >= K * Ncols) return;
    int k = idx / Ncols, c = idx - k * Ncols;
    Wt[c * K + k] = f2bf(W[idx]);
}

// ---- aggregation 1: aggx[d] = bf16( dis[d] * (xs[d] + sum_{s in in(d)} xs[s]) ) -----
// 4-way batched neighbor loop: 4 independent row-gathers in flight (latency-bound fix).

__global__ __launch_bounds__(256) void agg1_kernel(const u16* __restrict__ xs,
        const int* __restrict__ row_start, const int* __restrict__ csr,
        const float* __restrict__ dis, u16* __restrict__ aggx, int n) {
    int gid = blockIdx.x * blockDim.x + threadIdx.x;
    int w = gid >> 6, lane = gid & 63;
    if (w >= n) return;
    const uint2* base = (const uint2*)xs;       // 64 uint2 per 256-feat row
    uint2 v = base[(size_t)w * 64 + lane];      // self-loop seed
    float a0 = bflo(v.x), a1 = bfhi(v.x), a2 = bflo(v.y), a3 = bfhi(v.y);
    int b = row_start[w], e = row_start[w + 1];
    int i = b;
    for (; i + 4 <= e; i += 4) {
        int s0 = csr[i], s1 = csr[i + 1], s2 = csr[i + 2], s3 = csr[i + 3];
        uint2 u0 = base[(size_t)s0 * 64 + lane];
        uint2 u1 = base[(size_t)s1 * 64 + lane];
        uint2 u2 = base[(size_t)s2 * 64 + lane];
        uint2 u3 = base[(size_t)s3 * 64 + lane];
        a0 += (bflo(u0.x) + bflo(u1.x)) + (bflo(u2.x) + bflo(u3.x));
        a1 += (bfhi(u0.x) + bfhi(u1.x)) + (bfhi(u2.x) + bfhi(u3.x));
        a2 += (bflo(u0.y) + bflo(u1.y)) + (bflo(u2.y) + bflo(u3.y));
        a3 += (bfhi(u0.y) + bfhi(u1.y)) + (bfhi(u2.y) + bfhi(u3.y));
    }
    for (; i < e; ++i) {
        int s = csr[i];
        uint2 u = base[(size_t)s * 64 + lane];
        a0 += bflo(u.x); a1 += bfhi(u.x); a2 += bflo(u.y); a3 += bfhi(u.y);
    }
    float dd = dis[w];
    uint2 o;
    o.x = (unsigned)f2bf(a0 * dd) | ((unsigned)f2bf(a1 * dd) << 16);
    o.y = (unsigned)f2bf(a2 * dd) | ((unsigned)f2bf(a3 * dd) << 16);
    ((uint2*)aggx)[(size_t)w * 64 + lane] = o;
}

// ---- GEMM1: feat1 = dropout(prelu(aggx @ W1 + b1)) -> bf16 ----------------
// A: M x 256 bf16 row-major; Bt: 512 x 256 bf16 (W1 transposed).
// mbits: bit-packed mask1 in pack_mask layout (8 u64 per row of 512).

__global__ __launch_bounds__(256) void gemm1_kernel(const u16* __restrict__ A,
        const u16* __restrict__ Bt, const float* __restrict__ bias,
        const float* __restrict__ a_p, const u64* __restrict__ mbits,
        u16* __restrict__ out, int M) {
    const int K = IN_DIM;
    __shared__ __align__(16) u16 As[BM * LDT];
    __shared__ __align__(16) u16 Bs[BN * LDT];
    int tid = threadIdx.x;
    int wave = tid >> 6, lane = tid & 63;
    int quad = lane >> 4, l16 = lane & 15;
    int wm = wave & 1, wn = wave >> 1;
    int m0 = blockIdx.x * BM, n0 = blockIdx.y * BN;

    floatx4 acc[4][4];
#pragma unroll
    for (int i = 0; i < 4; i++)
#pragma unroll
        for (int j = 0; j < 4; j++) acc[i][j] = (floatx4){0.f, 0.f, 0.f, 0.f};

    for (int k0 = 0; k0 < K; k0 += BK) {
        __syncthreads();
#pragma unroll
        for (int u = tid; u < 512; u += 256) {   // 128 rows x 4 uint4
            int row = u >> 2, seg = u & 3;
            uint4 av = make_uint4(0, 0, 0, 0);
            int gr = m0 + row;
            if (gr < M) av = *(const uint4*)&A[(size_t)gr * K + k0 + seg * 8];
            *(uint4*)&As[row * LDT + seg * 8] = av;
            uint4 bv = *(const uint4*)&Bt[(size_t)(n0 + row) * K + k0 + seg * 8];
            *(uint4*)&Bs[row * LDT + seg * 8] = bv;
        }
        __syncthreads();
        short8 af[4], bf8[4];
#pragma unroll
        for (int i = 0; i < 4; i++)
            af[i] = *(const short8*)&As[(wm * 64 + i * 16 + l16) * LDT + quad * 8];
#pragma unroll
        for (int i = 0; i < 4; i++)
            bf8[i] = *(const short8*)&Bs[(wn * 64 + i * 16 + l16) * LDT + quad * 8];
#pragma unroll
        for (int mt = 0; mt < 4; mt++)
#pragma unroll
            for (int nt = 0; nt < 4; nt++)
                acc[mt][nt] = __builtin_amdgcn_mfma_f32_16x16x32_bf16(
                    af[mt], bf8[nt], acc[mt][nt], 0, 0, 0);
    }

    // stage this block's mask bits (128 rows x 4 u64, stride 5 -> 5KB, alias As)
    u64* mb = (u64*)As;
    __syncthreads();
    for (int u = tid; u < BM * 4; u += 256) {
        int row = u >> 2, j = u & 3;
        int gr = m0 + row;
        u64 val = 0;
        if (gr < M) val = mbits[(size_t)gr * 8 + (n0 >> 8) * 4 + j];
        mb[row * 5 + j] = val;   // stride 5: quad x j pattern hits 16 distinct bank-pairs
    }
    __syncthreads();

    float alpha = a_p[0];
#pragma unroll
    for (int mt = 0; mt < 4; mt++) {
#pragma unroll
        for (int r = 0; r < 4; r++) {
            int lr = wm * 64 + mt * 16 + quad * 4 + r;   // local row in [0,128)
            int row = m0 + lr;
            if (row >= M) continue;
#pragma unroll
            for (int nt = 0; nt < 4; nt++) {
                int c64 = nt * 16 + l16;                 // col within wn's 64-col half
                int col = n0 + wn * 64 + c64;
                float v = acc[mt][nt][r] + bias[col];
                v = (v >= 0.f) ? v : alpha * v;
                u64 w = mb[lr * 5 + (l16 & 3)];          // j = col & 3 == l16 & 3
                int bit = ((n0 >> 2) + wn * 16 + nt * 4 + (l16 >> 2)) & 63;  // (col>>2)&63
                v = ((w >> bit) & 1ull) ? v * 2.0f : 0.0f;
                out[(size_t)row * H1 + col] = f2bf(v);
            }
        }
    }
}

// ---- GEMM2: ts = bf16( dis[row] * (feat1 @ W2) ) --------------------------
// A: M x 512 bf16; Bt: 128 x 512 bf16

__global__ __launch_bounds__(256) void gemm2_kernel(const u16* __restrict__ A,
        const u16* __restrict__ Bt, const float* __restrict__ dis,
        u16* __restrict__ out, int M) {
    const int K = H1;
    __shared__ __align__(16) u16 As[BM * LDT];
    __shared__ __align__(16) u16 Bs[BN * LDT];
    int tid = threadIdx.x;
    int wave = tid >> 6, lane = tid & 63;
    int quad = lane >> 4, l16 = lane & 15;
    int wm = wave & 1, wn = wave >> 1;
    int m0 = blockIdx.x * BM, n0 = 0;

    floatx4 acc[4][4];
#pragma unroll
    for (int i = 0; i < 4; i++)
#pragma unroll
        for (int j = 0; j < 4; j++) acc[i][j] = (floatx4){0.f, 0.f, 0.f, 0.f};

    for (int k0 = 0; k0 < K; k0 += BK) {
        __syncthreads();
#pragma unroll
        for (int u = tid; u < 512; u += 256) {
            int row = u >> 2, seg = u & 3;
            uint4 av = make_uint4(0, 0, 0, 0);
            int gr = m0 + row;
            if (gr < M) av = *(const uint4*)&A[(size_t)gr * K + k0 + seg * 8];
            *(uint4*)&As[row * LDT + seg * 8] = av;
            uint4 bv = *(const uint4*)&Bt[(size_t)(n0 + row) * K + k0 + seg * 8];
            *(uint4*)&Bs[row * LDT + seg * 8] = bv;
        }
        __syncthreads();
        short8 af[4], bf8[4];
#pragma unroll
        for (int i = 0; i < 4; i++)
            af[i] = *(const short8*)&As[(wm * 64 + i * 16 + l16) * LDT + quad * 8];
#pragma unroll
        for (int i = 0; i < 4; i++)
            bf8[i] = *(const short8*)&Bs[(wn * 64 + i * 16 + l16) * LDT + quad * 8];
#pragma unroll
        for (int mt = 0; mt < 4; mt++)
#pragma unroll
            for (int nt = 0; nt < 4; nt++)
                acc[mt][nt] = __builtin_amdgcn_mfma_f32_16x16x32_bf16(
                    af[mt], bf8[nt], acc[mt][nt], 0, 0, 0);
    }

#pragma unroll
    for (int mt = 0; mt < 4; mt++) {
#pragma unroll
        for (int r = 0; r < 4; r++) {
            int row = m0 + wm * 64 + mt * 16 + quad * 4 + r;
            if (row >= M) continue;
            float dd = dis[row];
#pragma unroll
            for (int nt = 0; nt < 4; nt++) {
                int col = n0 + wn * 64 + nt * 16 + l16;
                out[(size_t)row * H2 + col] = f2bf(acc[mt][nt][r] * dd);
            }
        }
    }
}

// ---- aggregation 2 + epilogue: out = dropout(prelu(dis[d]*(ts[d]+sum ts[s]) + b2)) --
// 4-way batched neighbor loop (same latency fix as agg1).

__global__ __launch_bounds__(256) void agg2_kernel(const u16* __restrict__ ts,
        const int* __restrict__ row_start, const int* __restrict__ csr,
        const float* __restrict__ dis, const float* __restrict__ b2,
        const float* __restrict__ a_p, const int* __restrict__ mask,
        float* __restrict__ out, int n) {
    int gid = blockIdx.x * blockDim.x + threadIdx.x;
    int w = gid >> 6, lane = gid & 63;
    if (w >= n) return;
    const unsigned* base = (const unsigned*)ts;   // 64 uints per 128-feat row
    unsigned v = base[(size_t)w * 64 + lane];
    float a0 = bflo(v), a1 = bfhi(v);
    int b = row_start[w], e = row_start[w + 1];
    int i = b;
    for (; i + 4 <= e; i += 4) {
        int s0 = csr[i], s1 = csr[i + 1], s2 = csr[i + 2], s3 = csr[i + 3];
        unsigned u0 = base[(size_t)s0 * 64 + lane];
        unsigned u1 = base[(size_t)s1 * 64 + lane];
        unsigned u2 = base[(size_t)s2 * 64 + lane];
        unsigned u3 = base[(size_t)s3 * 64 + lane];
        a0 += (bflo(u0) + bflo(u1)) + (bflo(u2) + bflo(u3));
        a1 += (bfhi(u0) + bfhi(u1)) + (bfhi(u2) + bfhi(u3));
    }
    for (; i < e; ++i) {
        int s = csr[i];
        unsigned u = base[(size_t)s * 64 + lane];
        a0 += bflo(u); a1 += bfhi(u);
    }
    float dd = dis[w];
    float alpha = a_p[0];
    int c0 = lane * 2;
    float v0 = dd * a0 + b2[c0];
    float v1 = dd * a1 + b2[c0 + 1];
    v0 = (v0 >= 0.f) ? v0 : alpha * v0;
    v1 = (v1 >= 0.f) ? v1 : alpha * v1;
    int2 m = ((const int2*)mask)[(size_t)w * 64 + lane];
    v0 = m.x ? v0 * 2.f : 0.f;
    v1 = m.y ? v1 * 2.f : 0.f;
    ((float2*)out)[(size_t)w * 64 + lane] = make_float2(v0, v1);
}

// ---- launch ---------------------------------------------------------------

extern "C" void kernel_launch(void* const* d_in, const int* in_sizes, int n_in,
                              void* d_out, int out_size, void* d_ws, size_t ws_size,
                              hipStream_t stream) {
    const float* x  = (const float*)d_in[0];
    const int* ei   = (const int*)d_in[1];
    const float* W1 = (const float*)d_in[2];
    const float* b1 = (const float*)d_in[3];
    const float* W2 = (const float*)d_in[4];
    const float* b2 = (const float*)d_in[5];
    const float* ap = (const float*)d_in[6];
    const int* mask1 = (const int*)d_in[7];
    const int* mask2 = (const int*)d_in[8];

    int n = in_sizes[0] / IN_DIM;      // 50000
    int E = in_sizes[1] / 2;           // 400000
    const int* srcA = ei;
    const int* dstA = ei + E;

    // ws layout (aliased lifetimes, ~64 MiB of the ~400 MB ws):
    //   feat1 (n*H1 bf16); first half doubles as xs before gemm1 writes feat1
    //   ts (doubles as mask1 bitpack before gemm2 writes ts), w1t, w2t,
    //   dis, counts, cursor, row_start, csr, partials
    // aggx (n*IN_DIM bf16) lives in d_out (dead before agg2 rewrites d_out).
    char* p = (char*)d_ws;
    auto alloc = [&](size_t bytes) {
        char* r = p;
        p += (bytes + 255) & ~(size_t)255;
        return r;
    };
    u16* feat1     = (u16*)alloc((size_t)n * H1 * 2);
    u16* xs        = feat1;            // alias: xs dead before feat1 is written
    u16* ts        = (u16*)alloc((size_t)n * H2 * 2);
    u64* bits1     = (u64*)ts;         // alias: bits1 dead before gemm2 writes ts
    u16* w1t       = (u16*)alloc((size_t)IN_DIM * H1 * 2);
    u16* w2t       = (u16*)alloc((size_t)H1 * H2 * 2);
    float* dis     = (float*)alloc((size_t)n * 4);
    int* counts    = (int*)alloc((size_t)n * 4);
    int* cursor    = (int*)alloc((size_t)n * 4);
    int* row_start = (int*)alloc(((size_t)n + 1) * 4);
    int* csr       = (int*)alloc((size_t)E * 4);
    int nscan = (n + SCAN_CHUNK - 1) / SCAN_CHUNK;
    int* partials  = (int*)alloc(((size_t)nscan + 1) * 4);
    u16* aggx      = (u16*)d_out;      // n*IN_DIM*2 == out_size*4 bytes exactly
    if ((size_t)(p - (char*)d_ws) > ws_size) return;  // ws too small: leave zeros

    const int tpb = 256;
    int total4 = n * H1 / 4;           // int4 elements; divisible by 256
    hipMemsetAsync(counts, 0, (size_t)n * 4, stream);
    pack_mask_kernel<<<(total4 + tpb - 1) / tpb, tpb, 0, stream>>>((const int4*)mask1,
        bits1, total4);
    hist_kernel<<<(E + tpb - 1) / tpb, tpb, 0, stream>>>(dstA, counts, E, n);
    partial_sum_kernel<<<nscan, tpb, 0, stream>>>(counts, partials, n);
    scan_partials_kernel<<<1, 64, 0, stream>>>(partials, nscan);
    scan_emit_kernel<<<nscan, tpb, 0, stream>>>(counts, partials, row_start, cursor, dis, n, nscan);
    scatter_kernel<<<(E + tpb - 1) / tpb, tpb, 0, stream>>>(srcA, dstA, cursor, csr, E, n);
    scale_cast_kernel<<<((n * (IN_DIM / 4)) + tpb - 1) / tpb, tpb, 0, stream>>>(x, dis, xs, n);
    transpose_cast_kernel<<<((IN_DIM * H1) + tpb - 1) / tpb, tpb, 0, stream>>>(W1, w1t, IN_DIM, H1);
    transpose_cast_kernel<<<((H1 * H2) + tpb - 1) / tpb, tpb, 0, stream>>>(W2, w2t, H1, H2);
    agg1_kernel<<<(n * 64 + tpb - 1) / tpb, tpb, 0, stream>>>(xs, row_start, csr, dis, aggx, n);
    dim3 g1((n + BM - 1) / BM, H1 / BN);
    gemm1_kernel<<<g1, tpb, 0, stream>>>(aggx, w1t, b1, ap, bits1, feat1, n);
    dim3 g2((n + BM - 1) / BM, 1);
    gemm2_kernel<<<g2, tpb, 0, stream>>>(feat1, w2t, dis, ts, n);
    agg2_kernel<<<(n * 64 + tpb - 1) / tpb, tpb, 0, stream>>>(ts, row_start, csr, dis, b2, ap,
                                                              mask2, (float*)d_out, n);
}